// Round 4
// baseline (19.862 us; speedup 1.0000x reference)
//
#include <hip/hip_runtime.h>

#define NOUT 4096
#define AH_OFF 0
#define AL_OFF (256*1024)
#define EW_OFF (512*1024)

typedef _Float16 f16x8 __attribute__((ext_vector_type(8)));
typedef __fp16   h16x2 __attribute__((ext_vector_type(2)));
typedef float    f32x4 __attribute__((ext_vector_type(4)));

// ws layout:
//   AH : _Float16[8][128][128] hi plane   @ 0      (256 KB)
//   AL : _Float16[8][128][128] lo plane   @ 256 KB (256 KB)
//   EwT: Ew hi/lo in MFMA-fragment order  @ 512 KB (2 MB)
//        byte_off(tile,ks,mf,plane,lane) = (((tile*4+ks)*2+mf)*2+plane)*1024 + lane*16
//        frag elem j: Ew[n = tile*32+mf*16+(lane&15)][w = ks*32+(lane>>4)*8+j]

__global__ __launch_bounds__(256) void prep_kernel(
    const float* __restrict__ act, const float* __restrict__ mu,
    const float* __restrict__ sigma, char* __restrict__ ws)
{
    const int t = blockIdx.x * 256 + threadIdx.x;   // 0..65535

    // ---- A -> f16 hi/lo, 2 elems/thread (131072 floats total) ----
    float2 a = reinterpret_cast<const float2*>(act)[t];
    h16x2 ahi = __builtin_amdgcn_cvt_pkrtz(a.x, a.y);
    h16x2 alo = __builtin_amdgcn_cvt_pkrtz(a.x - (float)ahi[0], a.y - (float)ahi[1]);
    reinterpret_cast<h16x2*>(ws + AH_OFF)[t] = ahi;
    reinterpret_cast<h16x2*>(ws + AL_OFF)[t] = alo;

    // ---- Ew fragment pair (hi+lo), 8 exps/thread ----
    const int l    = t & 63;
    float2 m, s;
    {
        const int mf   = (t >> 6) & 1;
        const int tile = t >> 9;                     // 0..127
        const int n    = tile * 32 + mf * 16 + (l & 15);
        m = reinterpret_cast<const float2*>(mu)[n];
        s = reinterpret_cast<const float2*>(sigma)[n];
    }
    const int ks = (t >> 7) & 3;
    const int w0 = ks * 32 + (l >> 4) * 8;
    float inv = 0.5f / (s.y * s.y);
    float e[8];
    #pragma unroll
    for (int j = 0; j < 8; ++j) {
        float d = (float)(w0 + j) * (1.0f / 128.0f) - m.y;
        e[j] = __expf(-d * d * inv);
    }
    f16x8 hi, lo;
    #pragma unroll
    for (int j = 0; j < 8; j += 2) {
        h16x2 h2 = __builtin_amdgcn_cvt_pkrtz(e[j], e[j + 1]);
        h16x2 l2 = __builtin_amdgcn_cvt_pkrtz(e[j] - (float)h2[0], e[j + 1] - (float)h2[1]);
        hi[j] = (_Float16)(float)h2[0]; hi[j + 1] = (_Float16)(float)h2[1];
        lo[j] = (_Float16)(float)l2[0]; lo[j + 1] = (_Float16)(float)l2[1];
    }
    char* base = ws + EW_OFF;
    *reinterpret_cast<f16x8*>(base + (((size_t)(t >> 6) * 2 + 0) * 64 + l) * 16) = hi;
    *reinterpret_cast<f16x8*>(base + (((size_t)(t >> 6) * 2 + 1) * 64 + l) * 16) = lo;
}

__global__ __launch_bounds__(256) void gauss_main_kernel(
    const char* __restrict__ ws, const float* __restrict__ mu,
    const float* __restrict__ sigma, float* __restrict__ out)
{
    __shared__ float4 EwLDS[1024];   // 16 KB, fragment-ordered
    __shared__ float4 musig[32];
    __shared__ float  red[4][32];

    const int t    = threadIdx.x;
    const int wv   = t >> 6;
    const int lane = t & 63;
    const int lm   = lane & 15;
    const int lg   = lane >> 4;
    const int n0   = blockIdx.x * 32;
    const int b    = blockIdx.y;

    // ---- load Ew tile (16 KB) to regs, A prefetch, then LDS store ----
    const float4* ewsrc = reinterpret_cast<const float4*>(ws + EW_OFF + (size_t)blockIdx.x * 16384);
    float4 stg0 = ewsrc[t], stg1 = ewsrc[256 + t], stg2 = ewsrc[512 + t], stg3 = ewsrc[768 + t];

    const _Float16* AH = reinterpret_cast<const _Float16*>(ws + AH_OFF);
    const _Float16* AL = reinterpret_cast<const _Float16*>(ws + AL_OFF);
    const int h0 = wv * 32 + lm, h1 = h0 + 16;
    const _Float16* a0 = AH + ((b * 128 + h0) * 128 + lg * 8);
    const _Float16* a1 = AH + ((b * 128 + h1) * 128 + lg * 8);
    const _Float16* c0 = AL + ((b * 128 + h0) * 128 + lg * 8);
    const _Float16* c1 = AL + ((b * 128 + h1) * 128 + lg * 8);

    f16x8 pre[2][2][2];   // [slot][nh][plane], all indices compile-time
    #pragma unroll
    for (int s = 0; s < 2; ++s) {
        pre[s][0][0] = *reinterpret_cast<const f16x8*>(a0 + s * 32);
        pre[s][1][0] = *reinterpret_cast<const f16x8*>(a1 + s * 32);
        pre[s][0][1] = *reinterpret_cast<const f16x8*>(c0 + s * 32);
        pre[s][1][1] = *reinterpret_cast<const f16x8*>(c1 + s * 32);
    }

    if (t < 32) {
        float2 m = reinterpret_cast<const float2*>(mu)[n0 + t];
        float2 s = reinterpret_cast<const float2*>(sigma)[n0 + t];
        musig[t] = make_float4(m.x, m.y, 0.5f / (s.x * s.x), 0.5f / (s.y * s.y));
    }

    EwLDS[t] = stg0; EwLDS[256 + t] = stg1; EwLDS[512 + t] = stg2; EwLDS[768 + t] = stg3;
    __syncthreads();

    // ---- MFMA K-loop over w (4 k-steps of 32), 12 MFMA each ----
    const char* EwB = reinterpret_cast<const char*>(EwLDS);
    f32x4 acc[2][2] = {};   // [mf (n half)][nh (h half)]
    #pragma unroll
    for (int ks = 0; ks < 4; ++ks) {
        const int cur = ks & 1;
        f16x8 ah0 = pre[cur][0][0], ah1 = pre[cur][1][0];
        f16x8 al0 = pre[cur][0][1], al1 = pre[cur][1][1];
        if (ks < 2) {   // prefetch ks+2
            pre[cur][0][0] = *reinterpret_cast<const f16x8*>(a0 + (ks + 2) * 32);
            pre[cur][1][0] = *reinterpret_cast<const f16x8*>(a1 + (ks + 2) * 32);
            pre[cur][0][1] = *reinterpret_cast<const f16x8*>(c0 + (ks + 2) * 32);
            pre[cur][1][1] = *reinterpret_cast<const f16x8*>(c1 + (ks + 2) * 32);
        }
        #pragma unroll
        for (int mf = 0; mf < 2; ++mf) {
            f16x8 ewh = *reinterpret_cast<const f16x8*>(EwB + (((ks * 2 + mf) * 2 + 0) * 64 + lane) * 16);
            f16x8 ewl = *reinterpret_cast<const f16x8*>(EwB + (((ks * 2 + mf) * 2 + 1) * 64 + lane) * 16);
            acc[mf][0] = __builtin_amdgcn_mfma_f32_16x16x32_f16(ewh, ah0, acc[mf][0], 0, 0, 0);
            acc[mf][0] = __builtin_amdgcn_mfma_f32_16x16x32_f16(ewh, al0, acc[mf][0], 0, 0, 0);
            acc[mf][0] = __builtin_amdgcn_mfma_f32_16x16x32_f16(ewl, ah0, acc[mf][0], 0, 0, 0);
            acc[mf][1] = __builtin_amdgcn_mfma_f32_16x16x32_f16(ewh, ah1, acc[mf][1], 0, 0, 0);
            acc[mf][1] = __builtin_amdgcn_mfma_f32_16x16x32_f16(ewh, al1, acc[mf][1], 0, 0, 0);
            acc[mf][1] = __builtin_amdgcn_mfma_f32_16x16x32_f16(ewl, ah1, acc[mf][1], 0, 0, 0);
        }
    }

    // ---- epilogue: fold Eh (fp32), reduce over h (verified in r1/r2) ----
    const float gh0 = (float)h0 * (1.0f / 128.0f);
    const float gh1 = (float)h1 * (1.0f / 128.0f);
    float s8[2][4];
    #pragma unroll
    for (int mf = 0; mf < 2; ++mf)
        #pragma unroll
        for (int r = 0; r < 4; ++r) {
            int n = mf * 16 + 4 * lg + r;
            float4 ms = musig[n];
            float d0 = gh0 - ms.x, d1 = gh1 - ms.x;
            float e0 = __expf(-d0 * d0 * ms.z);
            float e1 = __expf(-d1 * d1 * ms.z);
            float v = e0 * acc[mf][0][r] + e1 * acc[mf][1][r];
            v += __shfl_xor(v, 1, 64);
            v += __shfl_xor(v, 2, 64);
            v += __shfl_xor(v, 4, 64);
            v += __shfl_xor(v, 8, 64);
            s8[mf][r] = v;
        }
    if (lm == 0) {
        #pragma unroll
        for (int mf = 0; mf < 2; ++mf)
            #pragma unroll
            for (int r = 0; r < 4; ++r)
                red[wv][mf * 16 + 4 * lg + r] = s8[mf][r];
    }
    __syncthreads();

    if (t < 32) {
        float s = red[0][t] + red[1][t] + red[2][t] + red[3][t];
        out[b * NOUT + n0 + t] = s * (1.0f / 16384.0f);
    }
}

extern "C" void kernel_launch(void* const* d_in, const int* in_sizes, int n_in,
                              void* d_out, int out_size, void* d_ws, size_t ws_size,
                              hipStream_t stream) {
    const float* act   = (const float*)d_in[0];
    const float* mu    = (const float*)d_in[1];
    const float* sigma = (const float*)d_in[2];
    float* out = (float*)d_out;
    char* ws = (char*)d_ws;

    prep_kernel<<<256, 256, 0, stream>>>(act, mu, sigma, ws);
    dim3 grid(NOUT / 32, 8);   // (128, 8)
    gauss_main_kernel<<<grid, 256, 0, stream>>>(ws, mu, sigma, out);
}

// Round 5
// 14.664 us; speedup vs baseline: 1.3545x; 1.3545x over previous
//
#include <hip/hip_runtime.h>

#define NOUT 4096

typedef _Float16 f16x8 __attribute__((ext_vector_type(8)));
typedef __fp16   h16x2 __attribute__((ext_vector_type(2)));
typedef __fp16   h16x4 __attribute__((ext_vector_type(4)));
typedef __fp16   h16x8 __attribute__((ext_vector_type(8)));
typedef float    f32x4 __attribute__((ext_vector_type(4)));

__device__ __forceinline__ f16x8 cat4(h16x2 a, h16x2 b, h16x2 c, h16x2 d) {
    h16x4 ab = __builtin_shufflevector(a, b, 0, 1, 2, 3);
    h16x4 cd = __builtin_shufflevector(c, d, 0, 1, 2, 3);
    h16x8 v  = __builtin_shufflevector(ab, cd, 0, 1, 2, 3, 4, 5, 6, 7);
    return __builtin_bit_cast(f16x8, v);
}

// 8 f32 -> f16 hi + f16 lo fragments (hi/lo split for accuracy)
__device__ __forceinline__ void cvtfrag(float4 p0, float4 p1, f16x8& hi, f16x8& lo) {
    h16x2 h0 = __builtin_amdgcn_cvt_pkrtz(p0.x, p0.y);
    h16x2 h1 = __builtin_amdgcn_cvt_pkrtz(p0.z, p0.w);
    h16x2 h2 = __builtin_amdgcn_cvt_pkrtz(p1.x, p1.y);
    h16x2 h3 = __builtin_amdgcn_cvt_pkrtz(p1.z, p1.w);
    h16x2 l0 = __builtin_amdgcn_cvt_pkrtz(p0.x - (float)h0[0], p0.y - (float)h0[1]);
    h16x2 l1 = __builtin_amdgcn_cvt_pkrtz(p0.z - (float)h1[0], p0.w - (float)h1[1]);
    h16x2 l2 = __builtin_amdgcn_cvt_pkrtz(p1.x - (float)h2[0], p1.y - (float)h2[1]);
    h16x2 l3 = __builtin_amdgcn_cvt_pkrtz(p1.z - (float)h3[0], p1.w - (float)h3[1]);
    hi = cat4(h0, h1, h2, h3);
    lo = cat4(l0, l1, l2, l3);
}

// corr[b,n] = (1/16384) * sum_h Eh[h,n] * sum_w Ew[w,n] * A[b,h,w]
// MFMA 16x16x32 f16: M=n (Ew, hi/lo from LDS in fragment order),
//                    N=h (A rows, hi/lo converted in-register from global f32),
//                    K=w. Eh folded in fp32 at the epilogue.
__global__ __launch_bounds__(256, 4) void gauss_fused_kernel(
    const float* __restrict__ act,    // [8][128][128]
    const float* __restrict__ mu,     // [4096][2]
    const float* __restrict__ sigma,  // [4096][2]
    float* __restrict__ out)          // [8][4096]
{
    __shared__ f16x8  EwLDS[16][64];  // [(ks*2+mf)*2+plane][lane], 16 KB, fragment order
    __shared__ float4 musig[32];      // mux, muy, 0.5/sx^2, 0.5/sy^2
    __shared__ float  red[4][32];

    const int t    = threadIdx.x;
    const int wv   = t >> 6;
    const int lane = t & 63;
    const int lm   = lane & 15;
    const int lg   = lane >> 4;
    const int n0   = blockIdx.x * 32;
    const int b    = blockIdx.y;
    const float* Ab = act + b * 16384;

    // ---- issue A loads for ks=0,1 immediately (hide under Ew phase) ----
    const int h0 = wv * 32 + lm, h1 = h0 + 16;
    const float* r0 = Ab + h0 * 128 + lg * 8;
    const float* r1 = Ab + h1 * 128 + lg * 8;
    float4 pf[2][2][2];   // [slot][nh][half], all indices compile-time
    #pragma unroll
    for (int s = 0; s < 2; ++s) {
        pf[s][0][0] = *reinterpret_cast<const float4*>(r0 + s * 32);
        pf[s][0][1] = *reinterpret_cast<const float4*>(r0 + s * 32 + 4);
        pf[s][1][0] = *reinterpret_cast<const float4*>(r1 + s * 32);
        pf[s][1][1] = *reinterpret_cast<const float4*>(r1 + s * 32 + 4);
    }

    // ---- per-n params for epilogue ----
    if (t < 32) {
        float2 m = reinterpret_cast<const float2*>(mu)[n0 + t];
        float2 s = reinterpret_cast<const float2*>(sigma)[n0 + t];
        musig[t] = make_float4(m.x, m.y, 0.5f / (s.x * s.x), 0.5f / (s.y * s.y));
    }

    // ---- Ew -> LDS in fragment order: group g=t>>6 handles ks=g, mf=0,1 ----
    const int ksg = t >> 6;
    #pragma unroll
    for (int mf = 0; mf < 2; ++mf) {
        int n = n0 + mf * 16 + lm;
        float2 m = reinterpret_cast<const float2*>(mu)[n];
        float2 s = reinterpret_cast<const float2*>(sigma)[n];
        float c = 0.5f / (s.y * s.y);
        int w0 = ksg * 32 + lg * 8;
        float e[8];
        #pragma unroll
        for (int j = 0; j < 8; ++j) {
            float d = (float)(w0 + j) * (1.0f / 128.0f) - m.y;
            e[j] = __expf(-d * d * c);
        }
        f16x8 hi, lo;
        cvtfrag(make_float4(e[0], e[1], e[2], e[3]),
                make_float4(e[4], e[5], e[6], e[7]), hi, lo);
        EwLDS[(ksg * 2 + mf) * 2 + 0][lane] = hi;
        EwLDS[(ksg * 2 + mf) * 2 + 1][lane] = lo;
    }
    __syncthreads();

    // ---- MFMA K-loop over w (4 k-steps of 32), 12 MFMA each ----
    f32x4 acc[2][2] = {};   // [mf (n half)][nh (h half)]
    #pragma unroll
    for (int ks = 0; ks < 4; ++ks) {
        const int cur = ks & 1;
        f16x8 ah0, al0, ah1, al1;
        cvtfrag(pf[cur][0][0], pf[cur][0][1], ah0, al0);
        cvtfrag(pf[cur][1][0], pf[cur][1][1], ah1, al1);
        if (ks < 2) {   // prefetch ks+2
            pf[cur][0][0] = *reinterpret_cast<const float4*>(r0 + (ks + 2) * 32);
            pf[cur][0][1] = *reinterpret_cast<const float4*>(r0 + (ks + 2) * 32 + 4);
            pf[cur][1][0] = *reinterpret_cast<const float4*>(r1 + (ks + 2) * 32);
            pf[cur][1][1] = *reinterpret_cast<const float4*>(r1 + (ks + 2) * 32 + 4);
        }
        #pragma unroll
        for (int mf = 0; mf < 2; ++mf) {
            f16x8 ewh = EwLDS[(ks * 2 + mf) * 2 + 0][lane];
            f16x8 ewl = EwLDS[(ks * 2 + mf) * 2 + 1][lane];
            acc[mf][0] = __builtin_amdgcn_mfma_f32_16x16x32_f16(ewh, ah0, acc[mf][0], 0, 0, 0);
            acc[mf][0] = __builtin_amdgcn_mfma_f32_16x16x32_f16(ewh, al0, acc[mf][0], 0, 0, 0);
            acc[mf][0] = __builtin_amdgcn_mfma_f32_16x16x32_f16(ewl, ah0, acc[mf][0], 0, 0, 0);
            acc[mf][1] = __builtin_amdgcn_mfma_f32_16x16x32_f16(ewh, ah1, acc[mf][1], 0, 0, 0);
            acc[mf][1] = __builtin_amdgcn_mfma_f32_16x16x32_f16(ewh, al1, acc[mf][1], 0, 0, 0);
            acc[mf][1] = __builtin_amdgcn_mfma_f32_16x16x32_f16(ewl, ah1, acc[mf][1], 0, 0, 0);
        }
    }

    // ---- epilogue: fold Eh (fp32), reduce over h (verified r1/r2/r4) ----
    // D layout: col(h within 16) = lane&15, row(n within 16) = 4*lg + r
    const float gh0 = (float)h0 * (1.0f / 128.0f);
    const float gh1 = (float)h1 * (1.0f / 128.0f);
    float s8[2][4];
    #pragma unroll
    for (int mf = 0; mf < 2; ++mf)
        #pragma unroll
        for (int r = 0; r < 4; ++r) {
            int n = mf * 16 + 4 * lg + r;
            float4 ms = musig[n];
            float d0 = gh0 - ms.x, d1 = gh1 - ms.x;
            float e0 = __expf(-d0 * d0 * ms.z);
            float e1 = __expf(-d1 * d1 * ms.z);
            float v = e0 * acc[mf][0][r] + e1 * acc[mf][1][r];
            v += __shfl_xor(v, 1, 64);
            v += __shfl_xor(v, 2, 64);
            v += __shfl_xor(v, 4, 64);
            v += __shfl_xor(v, 8, 64);
            s8[mf][r] = v;
        }
    if (lm == 0) {
        #pragma unroll
        for (int mf = 0; mf < 2; ++mf)
            #pragma unroll
            for (int r = 0; r < 4; ++r)
                red[wv][mf * 16 + 4 * lg + r] = s8[mf][r];
    }
    __syncthreads();

    if (t < 32) {
        float s = red[0][t] + red[1][t] + red[2][t] + red[3][t];
        out[b * NOUT + n0 + t] = s * (1.0f / 16384.0f);
    }
}

extern "C" void kernel_launch(void* const* d_in, const int* in_sizes, int n_in,
                              void* d_out, int out_size, void* d_ws, size_t ws_size,
                              hipStream_t stream) {
    const float* act   = (const float*)d_in[0];
    const float* mu    = (const float*)d_in[1];
    const float* sigma = (const float*)d_in[2];
    float* out = (float*)d_out;

    dim3 grid(NOUT / 32, 8);   // (128, 8) = 1024 blocks, 4/CU
    gauss_fused_kernel<<<grid, 256, 0, stream>>>(act, mu, sigma, out);
}

// Round 6
// 13.243 us; speedup vs baseline: 1.4998x; 1.1073x over previous
//
#include <hip/hip_runtime.h>

#define NOUT 4096

typedef _Float16 f16x8 __attribute__((ext_vector_type(8)));
typedef __fp16   h16x2 __attribute__((ext_vector_type(2)));
typedef __fp16   h16x4 __attribute__((ext_vector_type(4)));
typedef __fp16   h16x8 __attribute__((ext_vector_type(8)));
typedef float    f32x4 __attribute__((ext_vector_type(4)));

__device__ __forceinline__ f16x8 cat4(h16x2 a, h16x2 b, h16x2 c, h16x2 d) {
    h16x4 ab = __builtin_shufflevector(a, b, 0, 1, 2, 3);
    h16x4 cd = __builtin_shufflevector(c, d, 0, 1, 2, 3);
    h16x8 v  = __builtin_shufflevector(ab, cd, 0, 1, 2, 3, 4, 5, 6, 7);
    return __builtin_bit_cast(f16x8, v);
}

// 8 f32 -> f16 hi + f16 lo fragments (hi/lo split for accuracy)
__device__ __forceinline__ void cvtfrag(float4 p0, float4 p1, f16x8& hi, f16x8& lo) {
    h16x2 h0 = __builtin_amdgcn_cvt_pkrtz(p0.x, p0.y);
    h16x2 h1 = __builtin_amdgcn_cvt_pkrtz(p0.z, p0.w);
    h16x2 h2 = __builtin_amdgcn_cvt_pkrtz(p1.x, p1.y);
    h16x2 h3 = __builtin_amdgcn_cvt_pkrtz(p1.z, p1.w);
    h16x2 l0 = __builtin_amdgcn_cvt_pkrtz(p0.x - (float)h0[0], p0.y - (float)h0[1]);
    h16x2 l1 = __builtin_amdgcn_cvt_pkrtz(p0.z - (float)h1[0], p0.w - (float)h1[1]);
    h16x2 l2 = __builtin_amdgcn_cvt_pkrtz(p1.x - (float)h2[0], p1.y - (float)h2[1]);
    h16x2 l3 = __builtin_amdgcn_cvt_pkrtz(p1.z - (float)h3[0], p1.w - (float)h3[1]);
    hi = cat4(h0, h1, h2, h3);
    lo = cat4(l0, l1, l2, l3);
}

// corr[b,n] = (1/16384) * sum_h Eh[h,n] * sum_w Ew[w,n] * A[b,h,w]
// 64-n tile, 512 threads: wave wv owns h-rows [wv*16, wv*16+16).
// MFMA 16x16x32 f16: M=n (Ew hi/lo from LDS, fragment order),
//                    N=h (A rows, hi/lo in-register from global f32), K=w.
__global__ __launch_bounds__(512, 4) void gauss_fused64_kernel(
    const float* __restrict__ act,    // [8][128][128]
    const float* __restrict__ mu,     // [4096][2]
    const float* __restrict__ sigma,  // [4096][2]
    float* __restrict__ out)          // [8][4096]
{
    __shared__ f16x8  EwLDS[16][2][64];   // [ks*4+mf][plane][lane], 32 KB
    __shared__ float4 musig[64];          // mux, muy, 0.5/sx^2, 0.5/sy^2
    __shared__ float  red[8][64];         // 2 KB

    const int t    = threadIdx.x;
    const int wv   = t >> 6;        // 0..7
    const int lane = t & 63;
    const int lm   = lane & 15;
    const int lg   = lane >> 4;
    const int n0   = blockIdx.x * 64;
    const int b    = blockIdx.y;
    const float* Ab = act + b * 16384;

    // ---- latency-critical loads FIRST: they gate the Ew phase & barrier ----
    // combos c = 2*wv, 2*wv+1; c -> ks = c>>2, mf = c&3
    const int cA = 2 * wv, cB = 2 * wv + 1;
    float2 mA = reinterpret_cast<const float2*>(mu)[n0 + (cA & 3) * 16 + lm];
    float2 sA = reinterpret_cast<const float2*>(sigma)[n0 + (cA & 3) * 16 + lm];
    float2 mB = reinterpret_cast<const float2*>(mu)[n0 + (cB & 3) * 16 + lm];
    float2 sB = reinterpret_cast<const float2*>(sigma)[n0 + (cB & 3) * 16 + lm];
    if (t < 64) {
        float2 m = reinterpret_cast<const float2*>(mu)[n0 + t];
        float2 s = reinterpret_cast<const float2*>(sigma)[n0 + t];
        musig[t] = make_float4(m.x, m.y, 0.5f / (s.x * s.x), 0.5f / (s.y * s.y));
    }

    // ---- A prefetch for ks=0,1 (hi latency hidden under Ew phase) ----
    const int h = wv * 16 + lm;
    const float* r0 = Ab + h * 128 + lg * 8;
    float4 pf[2][2];   // [slot][half]
    #pragma unroll
    for (int s = 0; s < 2; ++s) {
        pf[s][0] = *reinterpret_cast<const float4*>(r0 + s * 32);
        pf[s][1] = *reinterpret_cast<const float4*>(r0 + s * 32 + 4);
    }

    // ---- Ew -> LDS in fragment order (each value computed once per block) ----
    #pragma unroll
    for (int i = 0; i < 2; ++i) {
        const int c  = 2 * wv + i;
        const int ks = c >> 2;
        const int w0 = ks * 32 + lg * 8;
        float2 m = i ? mB : mA;
        float2 s = i ? sB : sA;
        float cc = 0.5f / (s.y * s.y);
        float e[8];
        #pragma unroll
        for (int j = 0; j < 8; ++j) {
            float d = (float)(w0 + j) * (1.0f / 128.0f) - m.y;
            e[j] = __expf(-d * d * cc);
        }
        f16x8 hi, lo;
        cvtfrag(make_float4(e[0], e[1], e[2], e[3]),
                make_float4(e[4], e[5], e[6], e[7]), hi, lo);
        EwLDS[c][0][lane] = hi;
        EwLDS[c][1][lane] = lo;
    }
    __syncthreads();

    // ---- MFMA K-loop over w (4 k-steps of 32), 12 MFMA each ----
    f32x4 acc[4] = {};   // [mf]
    #pragma unroll
    for (int ks = 0; ks < 4; ++ks) {
        const int cur = ks & 1;
        f16x8 ah, al;
        cvtfrag(pf[cur][0], pf[cur][1], ah, al);
        if (ks < 2) {   // prefetch ks+2
            pf[cur][0] = *reinterpret_cast<const float4*>(r0 + (ks + 2) * 32);
            pf[cur][1] = *reinterpret_cast<const float4*>(r0 + (ks + 2) * 32 + 4);
        }
        #pragma unroll
        for (int mf = 0; mf < 4; ++mf) {
            f16x8 ewh = EwLDS[ks * 4 + mf][0][lane];
            f16x8 ewl = EwLDS[ks * 4 + mf][1][lane];
            acc[mf] = __builtin_amdgcn_mfma_f32_16x16x32_f16(ewh, ah, acc[mf], 0, 0, 0);
            acc[mf] = __builtin_amdgcn_mfma_f32_16x16x32_f16(ewh, al, acc[mf], 0, 0, 0);
            acc[mf] = __builtin_amdgcn_mfma_f32_16x16x32_f16(ewl, ah, acc[mf], 0, 0, 0);
        }
    }

    // ---- epilogue: fold Eh (fp32), reduce over this wave's 16 h ----
    // D layout: col(h within 16) = lane&15, row(n within 16) = 4*lg + r
    const float gh = (float)h * (1.0f / 128.0f);
    float sv[4][4];
    #pragma unroll
    for (int mf = 0; mf < 4; ++mf)
        #pragma unroll
        for (int r = 0; r < 4; ++r) {
            int n = mf * 16 + 4 * lg + r;
            float4 ms = musig[n];
            float d = gh - ms.x;
            float v = __expf(-d * d * ms.z) * acc[mf][r];
            v += __shfl_xor(v, 1, 64);
            v += __shfl_xor(v, 2, 64);
            v += __shfl_xor(v, 4, 64);
            v += __shfl_xor(v, 8, 64);
            sv[mf][r] = v;            // lanes with lm==0 hold the 16-h sum
        }
    if (lm == 0) {
        #pragma unroll
        for (int mf = 0; mf < 4; ++mf)
            #pragma unroll
            for (int r = 0; r < 4; ++r)
                red[wv][mf * 16 + 4 * lg + r] = sv[mf][r];
    }
    __syncthreads();

    if (t < 64) {
        float s = 0.f;
        #pragma unroll
        for (int w = 0; w < 8; ++w)
            s += red[w][t];
        out[b * NOUT + n0 + t] = s * (1.0f / 16384.0f);
    }
}

extern "C" void kernel_launch(void* const* d_in, const int* in_sizes, int n_in,
                              void* d_out, int out_size, void* d_ws, size_t ws_size,
                              hipStream_t stream) {
    const float* act   = (const float*)d_in[0];
    const float* mu    = (const float*)d_in[1];
    const float* sigma = (const float*)d_in[2];
    float* out = (float*)d_out;

    dim3 grid(NOUT / 64, 8);   // (64, 8) = 512 blocks, 2/CU, 4 waves/SIMD
    gauss_fused64_kernel<<<grid, 512, 0, stream>>>(act, mu, sigma, out);
}